// Round 20
// baseline (4444.006 us; speedup 1.0000x reference)
//
#include <hip/hip_runtime.h>

// Bidirectional GRU, persistent-kernel. Round 20.
// Base: r17 (3960us; XCD-local sc0 comm + unanimous vote; r19 spread-flags
// reverted - null). r19 ledger: all protocol micro-terms nulled; remaining
// ~1.5-2us/step traced to the ih waves' x-prefetch HBM stall sitting on the
// chain via B1 (post-flag issue leaves only ~0.3us window; conversion stalls
// ~1us+; gates wait at B1 for ih's Cp write).
// r20 STRUCTURE: ih waves exit publish/drain entirely.
//  - GATES ON HH WAVES ONLY: 256 lanes x 2 outputs (batch gb and gb+16, same
//    col). Publish 2 packed pairs/even-lane, hh-only vmcnt(0) drain, hh-side
//    out/hlast stores. Cp/B1 unchanged.
//  - IH WAVES: convert x(t) -> ISSUE x(t+1) PREFETCH AT TOP OF STEP (window
//    = full step >> HBM latency) -> 24 MFMA -> Cp -> B1 -> B2. No VM drains
//    in their path ever.
//  - Flag by tid0 after B2 (barrier orders it after hh drains).

#define T_LEN 1024
#define B_SZ  32
#define D_SZ  512
#define H_SZ  512
#define NWG_DIR 32
#define JW 16
#define NTHR 512

typedef __attribute__((ext_vector_type(8))) _Float16 half8;
typedef __attribute__((ext_vector_type(4))) float f32x4;
typedef __attribute__((ext_vector_type(4))) int int4v;

__device__ __forceinline__ _Float16 f2h(float f) { return (_Float16)f; }
__device__ __forceinline__ float sigm_f(float v) {
  return __builtin_amdgcn_rcpf(1.f + __expf(-v));
}
__device__ __forceinline__ float tanh_f(float v) {
  return 1.f - 2.f * __builtin_amdgcn_rcpf(1.f + __expf(2.f * v));
}
__device__ __forceinline__ void bar_lgkm() {
  asm volatile("s_waitcnt lgkmcnt(0)\ns_barrier" ::: "memory");
}

__global__ __launch_bounds__(NTHR, 2)
void gru2_persistent(const float* __restrict__ x,
                     const float* __restrict__ wih_fw, const float* __restrict__ whh_fw,
                     const float* __restrict__ bih_fw, const float* __restrict__ bhh_fw,
                     const float* __restrict__ wih_bw, const float* __restrict__ whh_bw,
                     const float* __restrict__ bih_bw, const float* __restrict__ bhh_bw,
                     float* __restrict__ out,
                     unsigned* __restrict__ hexu,
                     unsigned* __restrict__ flags,
                     unsigned* __restrict__ xcdmap,
                     unsigned* __restrict__ gbar,
                     unsigned* __restrict__ slowCnt)
{
  const int bid = blockIdx.x;
  const int dir = bid & 7;
  if (dir >= 2) return;            // 192 helper blocks exit
  const int g = bid >> 3;          // slice 0..31

  __shared__ float Cp[24 * 272];
  __shared__ float biasLds[96];
  __shared__ int fastSh;

  const int tid  = threadIdx.x;
  const int wave = tid >> 6;
  const int lane = tid & 63;

  const float* wih = dir ? wih_bw : wih_fw;
  const float* whh = dir ? whh_bw : whh_fw;
  const float* bih = dir ? bih_bw : bih_fw;
  const float* bhh = dir ? bhh_bw : bhh_fw;

  if (tid < 48) {
    int grow = (tid >> 4) * H_SZ + g * JW + (tid & 15);
    biasLds[tid]      = bih[grow];
    biasLds[48 + tid] = bhh[grow];
  }

  // ---- phase 1: local detection (r16/r17 machinery, proven) ----
  {
    unsigned xcc;
    asm volatile("s_getreg_b32 %0, hwreg(20, 0, 32)" : "=s"(xcc));  // XCC_ID
    if (tid == 0)
      __hip_atomic_store(&xcdmap[dir * NWG_DIR + g], xcc + 1u,
                         __ATOMIC_RELAXED, __HIP_MEMORY_SCOPE_AGENT);
    if (wave == 0) {
      unsigned v = 0u; int bud = 1 << 17; bool ok = true;
      for (;;) {
        v = __hip_atomic_load(&xcdmap[lane], __ATOMIC_RELAXED,
                              __HIP_MEMORY_SCOPE_AGENT);
        if (__all(v != 0u)) break;
        if (--bud < 0) { ok = false; break; }
        __builtin_amdgcn_s_sleep(8);
      }
      const unsigned ref0 = __shfl(v, 0);
      const unsigned ref1 = __shfl(v, NWG_DIR);
      const bool uni = __all((lane < NWG_DIR) ? (v == ref0) : (v == ref1));
      if (lane == 0) fastSh = (ok && uni && ref0 != ref1) ? 1 : 0;
    }
  }
  __syncthreads();
  __builtin_amdgcn_fence(__ATOMIC_ACQUIRE, "agent");
  __syncthreads();

  // ---- phase 2: unanimous vote + grid barrier (~50ms cap) ----
  if (tid == 0) {
    if (!fastSh)
      __hip_atomic_fetch_add(slowCnt, 1u, __ATOMIC_RELAXED,
                             __HIP_MEMORY_SCOPE_AGENT);
    asm volatile("s_waitcnt vmcnt(0)" ::: "memory");
    __hip_atomic_fetch_add(gbar, 1u, __ATOMIC_RELAXED, __HIP_MEMORY_SCOPE_AGENT);
    int bud = 1 << 18; bool arrived = true;
    while (__hip_atomic_load(gbar, __ATOMIC_RELAXED,
                             __HIP_MEMORY_SCOPE_AGENT) < 64u) {
      if (--bud < 0) { arrived = false; break; }
      __builtin_amdgcn_s_sleep(4);
    }
    unsigned sv = __hip_atomic_load(slowCnt, __ATOMIC_RELAXED,
                                    __HIP_MEMORY_SCOPE_AGENT);
    fastSh = (arrived && sv == 0u && fastSh) ? 1 : 0;
  }
  __syncthreads();
  const bool fast = (fastSh != 0);

  const bool isHh = (wave >= 4);
  const int  wv   = wave & 3;
  const int  wm   = wv & 1;
  const int  kh   = wv >> 1;

  // ---- weight B-fragments in registers (layout proven r1-r19) ----
  half8 Bf[3][8];
  {
    const float* W = isHh ? whh : wih;
    #pragma unroll
    for (int gam = 0; gam < 3; ++gam) {
      const int row = gam * H_SZ + g * JW + (lane & 15);
      #pragma unroll
      for (int i = 0; i < 8; ++i) {
        const float* src = W + (size_t)row * D_SZ + (kh * 8 + i) * 32 + ((lane >> 4) << 3);
        float4 v0 = *(const float4*)(src);
        float4 v1 = *(const float4*)(src + 4);
        half8 b;
        b[0]=f2h(v0.x); b[1]=f2h(v0.y); b[2]=f2h(v0.z); b[3]=f2h(v0.w);
        b[4]=f2h(v1.x); b[5]=f2h(v1.y); b[6]=f2h(v1.z); b[7]=f2h(v1.w);
        Bf[gam][i] = b;
      }
    }
  }

  const int arow = wm * 16 + (lane & 15);
  const int koff = (lane >> 4) << 3;
  const float* const xwavebase = x + (size_t)arow * T_LEN * D_SZ + kh * 256 + koff;

  float4 xn[16];
  if (!isHh) {
    const int t0 = dir ? (T_LEN - 1) : 0;
    const float* base = xwavebase + (size_t)t0 * D_SZ;
    #pragma unroll
    for (int i = 0; i < 8; ++i) {
      xn[2*i]   = *(const float4*)(base + i * 32);
      xn[2*i+1] = *(const float4*)(base + i * 32 + 4);
    }
  }
  __syncthreads();

  // hh gate-lane geometry: q = tid-256 in [0,256); outputs (gb0,gj2) and
  // (gb0+16,gj2). Recurrent state: 2 floats per hh lane.
  const int q   = tid - 256;
  const int gb0 = (q >> 4) & 15;
  const int gj2 = q & 15;
  float hreg0 = 0.f, hreg1 = 0.f;
  float* hlast = out + (size_t)B_SZ * T_LEN * (2 * H_SZ) + (size_t)dir * B_SZ * H_SZ;
  const unsigned* const fa = flags + (size_t)dir * NWG_DIR + kh * 16 + (lane & 15);
  int pollbud = 1 << 21;

  for (int s = 0; s < T_LEN; ++s) {
    const int t = dir ? (T_LEN - 1 - s) : s;
    const bool hasNext = (s + 1 < T_LEN);

    f32x4 acc[3] = {{0.f,0.f,0.f,0.f},{0.f,0.f,0.f,0.f},{0.f,0.f,0.f,0.f}};

    if (!isHh) {
      // convert prefetched x(t); ISSUE x(t+1) IMMEDIATELY (full-step window;
      // no VM drain ever touches this wave, so the load is never force-drained)
      half8 a[8];
      #pragma unroll
      for (int i = 0; i < 8; ++i) {
        float4 u = xn[2*i], w = xn[2*i+1];
        half8 h;
        h[0]=f2h(u.x); h[1]=f2h(u.y); h[2]=f2h(u.z); h[3]=f2h(u.w);
        h[4]=f2h(w.x); h[5]=f2h(w.y); h[6]=f2h(w.z); h[7]=f2h(w.w);
        a[i] = h;
      }
      if (hasNext) {
        const int tn = dir ? (T_LEN - 2 - s) : (s + 1);
        const float* base = xwavebase + (size_t)tn * D_SZ;
        #pragma unroll
        for (int i = 0; i < 8; ++i) {
          xn[2*i]   = *(const float4*)(base + i * 32);
          xn[2*i+1] = *(const float4*)(base + i * 32 + 4);
        }
      }
      #pragma unroll
      for (int i = 0; i < 8; ++i)
        #pragma unroll
        for (int gam = 0; gam < 3; ++gam)
          acc[gam] = __builtin_amdgcn_mfma_f32_16x16x32_f16(a[i], Bf[gam][i], acc[gam], 0, 0, 0);
    } else if (s > 0) {
      if (fast) {
        // ---- fast poll: 2-deep pipelined sc0 probes (budgeted)
        {
          unsigned va, vb;
          asm volatile("global_load_dword %0, %1, off sc0" : "=&v"(va) : "v"(fa));
          asm volatile("global_load_dword %0, %1, off sc0" : "=&v"(vb) : "v"(fa));
          for (;;) {
            asm volatile("s_waitcnt vmcnt(1)" ::: "memory");
            if (__all(va >= (unsigned)s)) break;
            if (--pollbud < 0) break;
            asm volatile("global_load_dword %0, %1, off sc0" : "=&v"(va) : "v"(fa));
            asm volatile("s_waitcnt vmcnt(1)" ::: "memory");
            if (__all(vb >= (unsigned)s)) break;
            if (--pollbud < 0) break;
            asm volatile("global_load_dword %0, %1, off sc0" : "=&v"(vb) : "v"(fa));
          }
          asm volatile("s_waitcnt vmcnt(0)" ::: "memory");
        }
        const char* p0 = (const char*)hexu
            + (((size_t)dir * 2 + ((s - 1) & 1)) * (B_SZ * (H_SZ / 2))) * 4
            + (size_t)arow * (H_SZ * 2) + (size_t)(kh * 256 + koff) * 2;
        int4v hv[8];
        asm volatile(
          "global_load_dwordx4 %0, %8, off sc0\n\t"
          "global_load_dwordx4 %1, %8, off offset:64 sc0\n\t"
          "global_load_dwordx4 %2, %8, off offset:128 sc0\n\t"
          "global_load_dwordx4 %3, %8, off offset:192 sc0\n\t"
          "global_load_dwordx4 %4, %8, off offset:256 sc0\n\t"
          "global_load_dwordx4 %5, %8, off offset:320 sc0\n\t"
          "global_load_dwordx4 %6, %8, off offset:384 sc0\n\t"
          "global_load_dwordx4 %7, %8, off offset:448 sc0\n\t"
          "s_waitcnt vmcnt(0)"
          : "=&v"(hv[0]), "=&v"(hv[1]), "=&v"(hv[2]), "=&v"(hv[3]),
            "=&v"(hv[4]), "=&v"(hv[5]), "=&v"(hv[6]), "=&v"(hv[7])
          : "v"(p0) : "memory");
        __builtin_amdgcn_sched_barrier(0);
        #pragma unroll
        for (int i = 0; i < 8; ++i) {
          half8 a = __builtin_bit_cast(half8, hv[i]);
          #pragma unroll
          for (int gam = 0; gam < 3; ++gam)
            acc[gam] = __builtin_amdgcn_mfma_f32_16x16x32_f16(a, Bf[gam][i], acc[gam], 0, 0, 0);
        }
      } else {
        // ---- slow path: LLC-scope poll (budgeted) + payload, r13 semantics
        {
          unsigned va, vb;
          asm volatile("global_load_dword %0, %1, off sc0 sc1" : "=&v"(va) : "v"(fa));
          asm volatile("global_load_dword %0, %1, off sc0 sc1" : "=&v"(vb) : "v"(fa));
          for (;;) {
            asm volatile("s_waitcnt vmcnt(1)" ::: "memory");
            if (__all(va >= (unsigned)s)) break;
            if (--pollbud < 0) break;
            asm volatile("global_load_dword %0, %1, off sc0 sc1" : "=&v"(va) : "v"(fa));
            asm volatile("s_waitcnt vmcnt(1)" ::: "memory");
            if (__all(vb >= (unsigned)s)) break;
            if (--pollbud < 0) break;
            asm volatile("global_load_dword %0, %1, off sc0 sc1" : "=&v"(vb) : "v"(fa));
          }
          asm volatile("s_waitcnt vmcnt(0)" ::: "memory");
        }
        const char* p0 = (const char*)hexu
            + (((size_t)dir * 2 + ((s - 1) & 1)) * (B_SZ * (H_SZ / 2))) * 4
            + (size_t)arow * (H_SZ * 2) + (size_t)(kh * 256 + koff) * 2;
        int4v hv[8];
        asm volatile(
          "global_load_dwordx4 %0, %8, off sc0 sc1\n\t"
          "global_load_dwordx4 %1, %8, off offset:64 sc0 sc1\n\t"
          "global_load_dwordx4 %2, %8, off offset:128 sc0 sc1\n\t"
          "global_load_dwordx4 %3, %8, off offset:192 sc0 sc1\n\t"
          "global_load_dwordx4 %4, %8, off offset:256 sc0 sc1\n\t"
          "global_load_dwordx4 %5, %8, off offset:320 sc0 sc1\n\t"
          "global_load_dwordx4 %6, %8, off offset:384 sc0 sc1\n\t"
          "global_load_dwordx4 %7, %8, off offset:448 sc0 sc1\n\t"
          "s_waitcnt vmcnt(0)"
          : "=&v"(hv[0]), "=&v"(hv[1]), "=&v"(hv[2]), "=&v"(hv[3]),
            "=&v"(hv[4]), "=&v"(hv[5]), "=&v"(hv[6]), "=&v"(hv[7])
          : "v"(p0) : "memory");
        __builtin_amdgcn_sched_barrier(0);
        #pragma unroll
        for (int i = 0; i < 8; ++i) {
          half8 a = __builtin_bit_cast(half8, hv[i]);
          #pragma unroll
          for (int gam = 0; gam < 3; ++gam)
            acc[gam] = __builtin_amdgcn_mfma_f32_16x16x32_f16(a, Bf[gam][i], acc[gam], 0, 0, 0);
        }
      }
    }

    // ---- write C-partials
    {
      const int src = isHh ? 1 : 0;
      #pragma unroll
      for (int gam = 0; gam < 3; ++gam) {
        float* cp = Cp + (size_t)(((src*2 + kh)*3 + gam)*2 + wm) * 272
                       + ((lane >> 4) << 2) * 17 + (lane & 15);
        #pragma unroll
        for (int vv2 = 0; vv2 < 4; ++vv2) cp[vv2 * 17] = acc[gam][vv2];
      }
    }
    bar_lgkm();   // B1: Cp ready

    // ---- gates: HH WAVES ONLY (2 outputs per lane: gb0 and gb0+16)
    float hn0S = 0.f, hn1S = 0.f;
    if (isHh) {
      #pragma unroll
      for (int half = 0; half < 2; ++half) {
        const int mb = half;          // gb0 in m-tile 0; gb0+16 in m-tile 1
        const int rb = gb0;
        float sih[3], shh[3];
        #pragma unroll
        for (int gam = 0; gam < 3; ++gam) {
          float aih = 0.f, ahh = 0.f;
          #pragma unroll
          for (int qk = 0; qk < 2; ++qk) {
            aih += Cp[(size_t)(((0*2+qk)*3+gam)*2 + mb) * 272 + rb * 17 + gj2];
            ahh += Cp[(size_t)(((1*2+qk)*3+gam)*2 + mb) * 272 + rb * 17 + gj2];
          }
          sih[gam] = aih + biasLds[gam * 16 + gj2];
          shh[gam] = ahh + biasLds[48 + gam * 16 + gj2];
        }
        const float r = sigm_f(sih[0] + shh[0]);
        const float z = sigm_f(sih[1] + shh[1]);
        const float n = tanh_f(sih[2] + r * shh[2]);
        const float hprev = half ? hreg1 : hreg0;
        const float hn = (1.f - z) * n + z * hprev;
        if (half) { hreg1 = hn; hn1S = hn; } else { hreg0 = hn; hn0S = hn; }
      }
      // publish both packed pairs (even-gj2 lanes; adjacent lanes = gj2^1)
      const float ho0 = __shfl_xor(hn0S, 1);
      const float ho1 = __shfl_xor(hn1S, 1);
      if ((gj2 & 1) == 0) {
        union { unsigned u; _Float16 h[2]; } p0u, p1u;
        p0u.h[0] = f2h(hn0S); p0u.h[1] = f2h(ho0);
        p1u.h[0] = f2h(hn1S); p1u.h[1] = f2h(ho1);
        const size_t pb = ((size_t)dir * 2 + (s & 1)) * (B_SZ * (H_SZ / 2));
        unsigned* hp0 = hexu + pb + (size_t)gb0 * (H_SZ / 2) + g * 8 + (gj2 >> 1);
        unsigned* hp1 = hexu + pb + (size_t)(gb0 + 16) * (H_SZ / 2) + g * 8 + (gj2 >> 1);
        if (fast) {
          asm volatile("global_store_dword %0, %1, off sc0"
                       :: "v"(hp0), "v"(p0u.u) : "memory");
          asm volatile("global_store_dword %0, %1, off sc0"
                       :: "v"(hp1), "v"(p1u.u) : "memory");
        } else {
          __hip_atomic_store(hp0, p0u.u, __ATOMIC_RELAXED, __HIP_MEMORY_SCOPE_AGENT);
          __hip_atomic_store(hp1, p1u.u, __ATOMIC_RELAXED, __HIP_MEMORY_SCOPE_AGENT);
        }
      }
      // hh-only drain: h stores acked (payload loads long retired)
      asm volatile("s_waitcnt vmcnt(0)" ::: "memory");
    }
    bar_lgkm();   // B2: hh drains done (barrier orders flag after them)
    if (tid == 0) {
      unsigned* fp = flags + (size_t)dir * NWG_DIR + g;
      const unsigned fv = (unsigned)(s + 1);
      if (fast)
        asm volatile("global_store_dword %0, %1, off sc0"
                     :: "v"(fp), "v"(fv) : "memory");
      else
        __hip_atomic_store(fp, fv, __ATOMIC_RELAXED, __HIP_MEMORY_SCOPE_AGENT);
    }

    // ---- off-chain tail: hh waves store out/hlast (2 outputs each)
    if (isHh) {
      out[((size_t)gb0 * T_LEN + t) * (2 * H_SZ) + dir * H_SZ + g * JW + gj2] = hn0S;
      out[((size_t)(gb0 + 16) * T_LEN + t) * (2 * H_SZ) + dir * H_SZ + g * JW + gj2] = hn1S;
      if (s == T_LEN - 1) {
        hlast[gb0 * H_SZ + g * JW + gj2] = hn0S;
        hlast[(gb0 + 16) * H_SZ + g * JW + gj2] = hn1S;
      }
    }
  }

  // release: write back dirty comm lines before kernel end
  __builtin_amdgcn_fence(__ATOMIC_RELEASE, "agent");
}

extern "C" void kernel_launch(void* const* d_in, const int* in_sizes, int n_in,
                              void* d_out, int out_size, void* d_ws, size_t ws_size,
                              hipStream_t stream) {
  const float* x      = (const float*)d_in[0];
  const float* wih_fw = (const float*)d_in[1];
  const float* whh_fw = (const float*)d_in[2];
  const float* bih_fw = (const float*)d_in[3];
  const float* bhh_fw = (const float*)d_in[4];
  const float* wih_bw = (const float*)d_in[5];
  const float* whh_bw = (const float*)d_in[6];
  const float* bih_bw = (const float*)d_in[7];
  const float* bhh_bw = (const float*)d_in[8];
  float* out = (float*)d_out;

  // ws: [0..255] xcdmap u32[64]; [256..511] flags u32[2][32]; [512..515] gbar;
  //     [516..519] slowCnt; pad to 1024; then hexu [2][2][32][256] u32 = 128 KB.
  const size_t CTRL_BYTES = 1024;
  const size_t HEX_BYTES  = (size_t)2 * 2 * B_SZ * (H_SZ / 2) * sizeof(unsigned);
  if (ws_size < CTRL_BYTES + HEX_BYTES) return;

  unsigned* xcdmap  = (unsigned*)d_ws;
  unsigned* flags   = (unsigned*)((char*)d_ws + 256);
  unsigned* gbar    = (unsigned*)((char*)d_ws + 512);
  unsigned* slowCnt = (unsigned*)((char*)d_ws + 516);
  unsigned* hexu    = (unsigned*)((char*)d_ws + CTRL_BYTES);

  hipMemsetAsync(d_ws, 0, CTRL_BYTES, stream);
  gru2_persistent<<<dim3(256), dim3(NTHR), 0, stream>>>(
      x, wih_fw, whh_fw, bih_fw, bhh_fw, wih_bw, whh_bw, bih_bw, bhh_bw,
      out, hexu, flags, xcdmap, gbar, slowCnt);
}

// Round 21
// 3927.855 us; speedup vs baseline: 1.1314x; 1.1314x over previous
//
#include <hip/hip_runtime.h>

// Bidirectional GRU, persistent-kernel. Round 21 = r16 VERBATIM (best hardened
// kernel: 3929us, absmax 0.0039, XCD-local sc0 comm + unanimous mode vote).
// r20's gate-redistribution regressed (4444us) and is reverted.
// FINAL-STATE RATIONALE: the op is serial-latency-bound (HBM 0.6%, MFMA 1.9%).
// 1024 inherently sequential steps x ~3.83us/step floor, where each step is a
// full 512-wide h broadcast among 32 CUs at the XCD-L2 coherence point:
// produce->L2 (~0.3us) + flag travel+detect (~0.7) + payload (~0.35) +
// GEMM/gates/barriers (~0.8) + max-over-32-paths jitter. Every term was
// individually attacked r3-r20; the 3 wins (fence removal, atomic batching,
// XCD-local scope) took 21.1ms -> 3.93ms; the remaining terms all nulled.

#define T_LEN 1024
#define B_SZ  32
#define D_SZ  512
#define H_SZ  512
#define NWG_DIR 32
#define JW 16
#define NTHR 512

typedef __attribute__((ext_vector_type(8))) _Float16 half8;
typedef __attribute__((ext_vector_type(4))) float f32x4;
typedef __attribute__((ext_vector_type(4))) int int4v;

__device__ __forceinline__ _Float16 f2h(float f) { return (_Float16)f; }
__device__ __forceinline__ float sigm_f(float v) {
  return __builtin_amdgcn_rcpf(1.f + __expf(-v));
}
__device__ __forceinline__ float tanh_f(float v) {
  return 1.f - 2.f * __builtin_amdgcn_rcpf(1.f + __expf(2.f * v));
}
__device__ __forceinline__ void bar_lgkm() {
  asm volatile("s_waitcnt lgkmcnt(0)\ns_barrier" ::: "memory");
}

__global__ __launch_bounds__(NTHR, 2)
void gru2_persistent(const float* __restrict__ x,
                     const float* __restrict__ wih_fw, const float* __restrict__ whh_fw,
                     const float* __restrict__ bih_fw, const float* __restrict__ bhh_fw,
                     const float* __restrict__ wih_bw, const float* __restrict__ whh_bw,
                     const float* __restrict__ bih_bw, const float* __restrict__ bhh_bw,
                     float* __restrict__ out,
                     unsigned* __restrict__ hexu,
                     unsigned* __restrict__ flags,
                     unsigned* __restrict__ xcdmap,
                     unsigned* __restrict__ gbar,
                     unsigned* __restrict__ slowCnt)
{
  const int bid = blockIdx.x;
  const int dir = bid & 7;
  if (dir >= 2) return;            // 192 helper blocks exit
  const int g = bid >> 3;          // slice 0..31

  __shared__ float Cp[24 * 272];
  __shared__ float biasLds[96];
  __shared__ int fastSh;

  const int tid  = threadIdx.x;
  const int wave = tid >> 6;
  const int lane = tid & 63;

  const float* wih = dir ? wih_bw : wih_fw;
  const float* whh = dir ? whh_bw : whh_fw;
  const float* bih = dir ? bih_bw : bih_fw;
  const float* bhh = dir ? bhh_bw : bhh_fw;

  if (tid < 48) {
    int grow = (tid >> 4) * H_SZ + g * JW + (tid & 15);
    biasLds[tid]      = bih[grow];
    biasLds[48 + tid] = bhh[grow];
  }

  // ---- phase 1: local detection from SHARED data (same function everywhere)
  {
    unsigned xcc;
    asm volatile("s_getreg_b32 %0, hwreg(20, 0, 32)" : "=s"(xcc));  // XCC_ID
    if (tid == 0)
      __hip_atomic_store(&xcdmap[dir * NWG_DIR + g], xcc + 1u,
                         __ATOMIC_RELAXED, __HIP_MEMORY_SCOPE_AGENT);
    if (wave == 0) {
      unsigned v = 0u; int bud = 1 << 17; bool ok = true;
      for (;;) {
        v = __hip_atomic_load(&xcdmap[lane], __ATOMIC_RELAXED,
                              __HIP_MEMORY_SCOPE_AGENT);
        if (__all(v != 0u)) break;
        if (--bud < 0) { ok = false; break; }
        __builtin_amdgcn_s_sleep(8);
      }
      const unsigned ref0 = __shfl(v, 0);
      const unsigned ref1 = __shfl(v, NWG_DIR);
      const bool uni = __all((lane < NWG_DIR) ? (v == ref0) : (v == ref1));
      if (lane == 0) fastSh = (ok && uni && ref0 != ref1) ? 1 : 0;
    }
  }
  __syncthreads();
  // acquire: drop stale clean L2 lines from the prior replay (per-WG)
  __builtin_amdgcn_fence(__ATOMIC_ACQUIRE, "agent");
  __syncthreads();

  // ---- phase 2: unanimous vote + grid barrier.
  // Order per WG: slow-vote -> vmcnt drain -> gbar arrival. A reader that
  // sees gbar==64 therefore sees every WG's vote.
  if (tid == 0) {
    if (!fastSh)
      __hip_atomic_fetch_add(slowCnt, 1u, __ATOMIC_RELAXED,
                             __HIP_MEMORY_SCOPE_AGENT);
    asm volatile("s_waitcnt vmcnt(0)" ::: "memory");
    __hip_atomic_fetch_add(gbar, 1u, __ATOMIC_RELAXED, __HIP_MEMORY_SCOPE_AGENT);
    int bud = 1 << 18; bool arrived = true;   // ~50ms cap
    while (__hip_atomic_load(gbar, __ATOMIC_RELAXED,
                             __HIP_MEMORY_SCOPE_AGENT) < 64u) {
      if (--bud < 0) { arrived = false; break; }
      __builtin_amdgcn_s_sleep(4);
    }
    unsigned sv = __hip_atomic_load(slowCnt, __ATOMIC_RELAXED,
                                    __HIP_MEMORY_SCOPE_AGENT);
    fastSh = (arrived && sv == 0u && fastSh) ? 1 : 0;
  }
  __syncthreads();
  const bool fast = (fastSh != 0);

  const bool isHh = (wave >= 4);
  const int  wv   = wave & 3;
  const int  wm   = wv & 1;
  const int  kh   = wv >> 1;

  // ---- weight B-fragments in registers (layout proven r1-r20) ----
  half8 Bf[3][8];
  {
    const float* W = isHh ? whh : wih;
    #pragma unroll
    for (int gam = 0; gam < 3; ++gam) {
      const int row = gam * H_SZ + g * JW + (lane & 15);
      #pragma unroll
      for (int i = 0; i < 8; ++i) {
        const float* src = W + (size_t)row * D_SZ + (kh * 8 + i) * 32 + ((lane >> 4) << 3);
        float4 v0 = *(const float4*)(src);
        float4 v1 = *(const float4*)(src + 4);
        half8 b;
        b[0]=f2h(v0.x); b[1]=f2h(v0.y); b[2]=f2h(v0.z); b[3]=f2h(v0.w);
        b[4]=f2h(v1.x); b[5]=f2h(v1.y); b[6]=f2h(v1.z); b[7]=f2h(v1.w);
        Bf[gam][i] = b;
      }
    }
  }

  const int arow = wm * 16 + (lane & 15);
  const int koff = (lane >> 4) << 3;
  const float* const xwavebase = x + (size_t)arow * T_LEN * D_SZ + kh * 256 + koff;

  float4 xn[16];
  if (!isHh) {
    const int t0 = dir ? (T_LEN - 1) : 0;
    const float* base = xwavebase + (size_t)t0 * D_SZ;
    #pragma unroll
    for (int i = 0; i < 8; ++i) {
      xn[2*i]   = *(const float4*)(base + i * 32);
      xn[2*i+1] = *(const float4*)(base + i * 32 + 4);
    }
  }
  __syncthreads();

  float hreg = 0.f;
  const int gb = tid >> 4;
  const int gj = tid & 15;
  float* hlast = out + (size_t)B_SZ * T_LEN * (2 * H_SZ) + (size_t)dir * B_SZ * H_SZ;
  const unsigned* const fa = flags + (size_t)dir * NWG_DIR + kh * 16 + (lane & 15);
  int pollbud = 1 << 21;   // total poll budget across all steps (both paths)

  for (int s = 0; s < T_LEN; ++s) {
    const int t = dir ? (T_LEN - 1 - s) : s;
    const bool hasNext = (s + 1 < T_LEN);

    f32x4 acc[3] = {{0.f,0.f,0.f,0.f},{0.f,0.f,0.f,0.f},{0.f,0.f,0.f,0.f}};

    if (!isHh) {
      half8 a[8];
      #pragma unroll
      for (int i = 0; i < 8; ++i) {
        float4 u = xn[2*i], w = xn[2*i+1];
        half8 h;
        h[0]=f2h(u.x); h[1]=f2h(u.y); h[2]=f2h(u.z); h[3]=f2h(u.w);
        h[4]=f2h(w.x); h[5]=f2h(w.y); h[6]=f2h(w.z); h[7]=f2h(w.w);
        a[i] = h;
      }
      #pragma unroll
      for (int i = 0; i < 8; ++i)
        #pragma unroll
        for (int gam = 0; gam < 3; ++gam)
          acc[gam] = __builtin_amdgcn_mfma_f32_16x16x32_f16(a[i], Bf[gam][i], acc[gam], 0, 0, 0);
    } else if (s > 0) {
      if (fast) {
        // ---- fast poll: sc0 probes at XCD-L2 latency (budget-bounded)
        for (;;) {
          unsigned vv;
          asm volatile("global_load_dword %0, %1, off sc0\ns_waitcnt vmcnt(0)"
                       : "=&v"(vv) : "v"(fa) : "memory");
          if (__all(vv >= (unsigned)s)) break;
          if (--pollbud < 0) break;
        }
        const char* p0 = (const char*)hexu
            + (((size_t)dir * 2 + ((s - 1) & 1)) * (B_SZ * (H_SZ / 2))) * 4
            + (size_t)arow * (H_SZ * 2) + (size_t)(kh * 256 + koff) * 2;
        int4v hv[8];
        asm volatile(
          "global_load_dwordx4 %0, %8, off sc0\n\t"
          "global_load_dwordx4 %1, %8, off offset:64 sc0\n\t"
          "global_load_dwordx4 %2, %8, off offset:128 sc0\n\t"
          "global_load_dwordx4 %3, %8, off offset:192 sc0\n\t"
          "global_load_dwordx4 %4, %8, off offset:256 sc0\n\t"
          "global_load_dwordx4 %5, %8, off offset:320 sc0\n\t"
          "global_load_dwordx4 %6, %8, off offset:384 sc0\n\t"
          "global_load_dwordx4 %7, %8, off offset:448 sc0\n\t"
          "s_waitcnt vmcnt(0)"
          : "=&v"(hv[0]), "=&v"(hv[1]), "=&v"(hv[2]), "=&v"(hv[3]),
            "=&v"(hv[4]), "=&v"(hv[5]), "=&v"(hv[6]), "=&v"(hv[7])
          : "v"(p0) : "memory");
        __builtin_amdgcn_sched_barrier(0);
        #pragma unroll
        for (int i = 0; i < 8; ++i) {
          half8 a = __builtin_bit_cast(half8, hv[i]);
          #pragma unroll
          for (int gam = 0; gam < 3; ++gam)
            acc[gam] = __builtin_amdgcn_mfma_f32_16x16x32_f16(a, Bf[gam][i], acc[gam], 0, 0, 0);
        }
      } else {
        // ---- slow path: 2-deep pipelined LLC poll (budgeted) + payload
        {
          unsigned va, vb;
          asm volatile("global_load_dword %0, %1, off sc0 sc1" : "=&v"(va) : "v"(fa));
          asm volatile("global_load_dword %0, %1, off sc0 sc1" : "=&v"(vb) : "v"(fa));
          for (;;) {
            asm volatile("s_waitcnt vmcnt(1)" ::: "memory");
            if (__all(va >= (unsigned)s)) break;
            if (--pollbud < 0) break;
            asm volatile("global_load_dword %0, %1, off sc0 sc1" : "=&v"(va) : "v"(fa));
            asm volatile("s_waitcnt vmcnt(1)" ::: "memory");
            if (__all(vb >= (unsigned)s)) break;
            if (--pollbud < 0) break;
            asm volatile("global_load_dword %0, %1, off sc0 sc1" : "=&v"(vb) : "v"(fa));
          }
          asm volatile("s_waitcnt vmcnt(0)" ::: "memory");
        }
        const char* p0 = (const char*)hexu
            + (((size_t)dir * 2 + ((s - 1) & 1)) * (B_SZ * (H_SZ / 2))) * 4
            + (size_t)arow * (H_SZ * 2) + (size_t)(kh * 256 + koff) * 2;
        int4v hv[8];
        asm volatile(
          "global_load_dwordx4 %0, %8, off sc0 sc1\n\t"
          "global_load_dwordx4 %1, %8, off offset:64 sc0 sc1\n\t"
          "global_load_dwordx4 %2, %8, off offset:128 sc0 sc1\n\t"
          "global_load_dwordx4 %3, %8, off offset:192 sc0 sc1\n\t"
          "global_load_dwordx4 %4, %8, off offset:256 sc0 sc1\n\t"
          "global_load_dwordx4 %5, %8, off offset:320 sc0 sc1\n\t"
          "global_load_dwordx4 %6, %8, off offset:384 sc0 sc1\n\t"
          "global_load_dwordx4 %7, %8, off offset:448 sc0 sc1\n\t"
          "s_waitcnt vmcnt(0)"
          : "=&v"(hv[0]), "=&v"(hv[1]), "=&v"(hv[2]), "=&v"(hv[3]),
            "=&v"(hv[4]), "=&v"(hv[5]), "=&v"(hv[6]), "=&v"(hv[7])
          : "v"(p0) : "memory");
        __builtin_amdgcn_sched_barrier(0);
        #pragma unroll
        for (int i = 0; i < 8; ++i) {
          half8 a = __builtin_bit_cast(half8, hv[i]);
          #pragma unroll
          for (int gam = 0; gam < 3; ++gam)
            acc[gam] = __builtin_amdgcn_mfma_f32_16x16x32_f16(a, Bf[gam][i], acc[gam], 0, 0, 0);
        }
      }
    }

    // ---- write C-partials
    {
      const int src = isHh ? 1 : 0;
      #pragma unroll
      for (int gam = 0; gam < 3; ++gam) {
        float* cp = Cp + (size_t)(((src*2 + kh)*3 + gam)*2 + wm) * 272
                       + ((lane >> 4) << 2) * 17 + (lane & 15);
        #pragma unroll
        for (int vv2 = 0; vv2 < 4; ++vv2) cp[vv2 * 17] = acc[gam][vv2];
      }
    }
    bar_lgkm();   // B1

    // ---- gates: compute h(s), publish h pair
    float hnS;
    {
      const int mb = gb >> 4, rb = gb & 15;
      float sih[3], shh[3];
      #pragma unroll
      for (int gam = 0; gam < 3; ++gam) {
        float aih = 0.f, ahh = 0.f;
        #pragma unroll
        for (int q = 0; q < 2; ++q) {
          aih += Cp[(size_t)(((0*2+q)*3+gam)*2 + mb) * 272 + rb * 17 + gj];
          ahh += Cp[(size_t)(((1*2+q)*3+gam)*2 + mb) * 272 + rb * 17 + gj];
        }
        sih[gam] = aih + biasLds[gam * 16 + gj];
        shh[gam] = ahh + biasLds[48 + gam * 16 + gj];
      }
      const float r = sigm_f(sih[0] + shh[0]);
      const float z = sigm_f(sih[1] + shh[1]);
      const float n = tanh_f(sih[2] + r * shh[2]);
      const float hn = (1.f - z) * n + z * hreg;
      hreg = hn;
      hnS = hn;

      const float hother = __shfl_xor(hn, 1);
      if ((gj & 1) == 0) {
        union { unsigned u; _Float16 h[2]; } pr;
        pr.h[0] = f2h(hn); pr.h[1] = f2h(hother);
        unsigned* hp = hexu + ((size_t)dir * 2 + (s & 1)) * (B_SZ * (H_SZ / 2))
                     + (size_t)gb * (H_SZ / 2) + (g * JW + gj) / 2;
        if (fast)
          asm volatile("global_store_dword %0, %1, off sc0"
                       :: "v"(hp), "v"(pr.u) : "memory");
        else
          __hip_atomic_store(hp, pr.u, __ATOMIC_RELAXED, __HIP_MEMORY_SCOPE_AGENT);
      }
    }
    asm volatile("s_waitcnt vmcnt(0)" ::: "memory");  // h-store acked
    bar_lgkm();   // B2
    if (tid == 0) {
      unsigned* fp = flags + (size_t)dir * NWG_DIR + g;
      const unsigned fv = (unsigned)(s + 1);
      if (fast)
        asm volatile("global_store_dword %0, %1, off sc0"
                     :: "v"(fp), "v"(fv) : "memory");
      else
        __hip_atomic_store(fp, fv, __ATOMIC_RELAXED, __HIP_MEMORY_SCOPE_AGENT);
    }

    // ---- off-chain tail
    out[((size_t)gb * T_LEN + t) * (2 * H_SZ) + dir * H_SZ + g * JW + gj] = hnS;
    if (s == T_LEN - 1) hlast[gb * H_SZ + g * JW + gj] = hnS;
    if (!isHh && hasNext) {
      const int tn = dir ? (T_LEN - 2 - s) : (s + 1);
      const float* base = xwavebase + (size_t)tn * D_SZ;
      #pragma unroll
      for (int i = 0; i < 8; ++i) {
        xn[2*i]   = *(const float4*)(base + i * 32);
        xn[2*i+1] = *(const float4*)(base + i * 32 + 4);
      }
    }
  }

  // release: write back dirty comm lines before kernel end
  __builtin_amdgcn_fence(__ATOMIC_RELEASE, "agent");
}

extern "C" void kernel_launch(void* const* d_in, const int* in_sizes, int n_in,
                              void* d_out, int out_size, void* d_ws, size_t ws_size,
                              hipStream_t stream) {
  const float* x      = (const float*)d_in[0];
  const float* wih_fw = (const float*)d_in[1];
  const float* whh_fw = (const float*)d_in[2];
  const float* bih_fw = (const float*)d_in[3];
  const float* bhh_fw = (const float*)d_in[4];
  const float* wih_bw = (const float*)d_in[5];
  const float* whh_bw = (const float*)d_in[6];
  const float* bih_bw = (const float*)d_in[7];
  const float* bhh_bw = (const float*)d_in[8];
  float* out = (float*)d_out;

  // ws: [0..255] xcdmap u32[64]; [256..511] flags u32[2][32]; [512..515] gbar;
  //     [516..519] slowCnt; pad to 1024; then hexu [2][2][32][256] u32 = 128 KB.
  const size_t CTRL_BYTES = 1024;
  const size_t HEX_BYTES  = (size_t)2 * 2 * B_SZ * (H_SZ / 2) * sizeof(unsigned);
  if (ws_size < CTRL_BYTES + HEX_BYTES) return;

  unsigned* xcdmap  = (unsigned*)d_ws;
  unsigned* flags   = (unsigned*)((char*)d_ws + 256);
  unsigned* gbar    = (unsigned*)((char*)d_ws + 512);
  unsigned* slowCnt = (unsigned*)((char*)d_ws + 516);
  unsigned* hexu    = (unsigned*)((char*)d_ws + CTRL_BYTES);

  hipMemsetAsync(d_ws, 0, CTRL_BYTES, stream);
  gru2_persistent<<<dim3(256), dim3(NTHR), 0, stream>>>(
      x, wih_fw, whh_fw, bih_fw, bhh_fw, wih_bw, whh_bw, bih_bw, bhh_bw,
      out, hexu, flags, xcdmap, gbar, slowCnt);
}